// Round 4
// baseline (34.761 us; speedup 1.0000x reference)
//
#include <hip/hip_runtime.h>
#include <hip/hip_bf16.h>

#define NO 32
#define HH 64
#define WW 1024
#define LL (HH * WW)
#define BB 8

typedef _Float16 h2 __attribute__((ext_vector_type(2)));
typedef unsigned u32x4 __attribute__((ext_vector_type(4)));

__device__ __forceinline__ h2 pk(float a, float b) {
    return __builtin_bit_cast(h2, __builtin_amdgcn_cvt_pkrtz(a, b));
}
__device__ __forceinline__ h2 fma2(h2 a, h2 b, h2 c) {
    return __builtin_elementwise_fma(a, b, c);
}
__device__ __forceinline__ h2 max2(h2 a, h2 b) {
    return __builtin_elementwise_max(a, b);
}
__device__ __forceinline__ h2 uash2(unsigned u) {
    return __builtin_bit_cast(h2, u);
}
__device__ __forceinline__ unsigned h2asu(h2 h) {
    return __builtin_bit_cast(unsigned, h);
}
__device__ __forceinline__ float uasf(unsigned u) {
    return __builtin_bit_cast(float, u);
}

// Pack weights once per launch: per o, 8 dwords =
// [pk(w0,w0), pk(w1,w1), pk(w2,w2), pk(w3,w3), pk(b,b), f32 w0, f32 w1, f32 b]
__global__ void prep_kernel(const float* __restrict__ cw,
                            const float* __restrict__ cb,
                            unsigned* __restrict__ ws) {
    const int o = threadIdx.x;
    if (o < NO) {
        const float w0 = cw[o * 4 + 0], w1 = cw[o * 4 + 1];
        const float w2 = cw[o * 4 + 2], w3 = cw[o * 4 + 3];
        const float b  = cb[o];
        unsigned* p = ws + o * 8;
        p[0] = h2asu(pk(w0, w0));
        p[1] = h2asu(pk(w1, w1));
        p[2] = h2asu(pk(w2, w2));
        p[3] = h2asu(pk(w3, w3));
        p[4] = h2asu(pk(b, b));
        p[5] = __builtin_bit_cast(unsigned, w0);
        p[6] = __builtin_bit_cast(unsigned, w1);
        p[7] = __builtin_bit_cast(unsigned, b);
    }
}

__global__ __launch_bounds__(256, 8) void pnc_kernel(
    const float* __restrict__ x, const float* __restrict__ X,
    const float* __restrict__ A, const float* __restrict__ E,
    const float* __restrict__ M, const unsigned* __restrict__ ws,
    float* __restrict__ out)
{
    // LDS: only the sincos tiles (f16x2 [sin,cos]) over 3 rows x 258 cols halo
    __shared__ unsigned tA[3 * 258];
    __shared__ unsigned tE[3 * 258];

    const int tid = threadIdx.x;
    const int bi  = blockIdx.x;
    const int b   = bi >> 8;           // 256 blocks per image (64 h x 4 col-quarters)
    const int h   = (bi >> 2) & 63;
    const int w0q = (bi & 3) << 8;
    const int w   = w0q + tid;
    const int l   = (h << 10) + w;

    const float* xb = x + b * LL;
    const float* Xb = X + b * LL;
    const float* Ab = A + b * LL;
    const float* Eb = E + b * LL;
    const float* Mb = M + b * LL;

    // ---- sincos tile fill: 3 rows x 258 cols of raw A, E angles ----
    for (int s = tid; s < 3 * 258; s += 256) {
        const int r = (s >= 516) ? 2 : ((s >= 258) ? 1 : 0);
        const int c = s - r * 258;
        int gh = h - 1 + r; gh = min(max(gh, 0), HH - 1);
        int gw = w0q - 1 + c; gw = min(max(gw, 0), WW - 1);
        const int gl = (gh << 10) + gw;
        const float a = Ab[gl], e = Eb[gl];
        float sa, ca, se, ce;
        __sincosf(a, &sa, &ca);
        __sincosf(e, &se, &ce);
        tA[s] = h2asu(pk(sa, ca));
        tE[s] = h2asu(pk(se, ce));
    }
    __syncthreads();

    // ---- center values ----
    const float xc = xb[l];
    const float Xc = Xb[l];
    const float Mc = Mb[l];
    const int   cl = tid + 1;
    const h2 cpA = uash2(tA[258 + cl]);
    const h2 cpE = uash2(tE[258 + cl]);
    const float sAc = (float)cpA.x, cAc = (float)cpA.y;
    const float sEc = (float)cpE.x, cEc = (float)cpE.y;

    // ---- 8 off-center taps -> 4 packed f16x2 pairs ----
    // tap order (di,dj): (-1,-1)(-1,0)(-1,1)(0,-1)(0,1)(1,-1)(1,0)(1,1)
    const int DI[8] = {-1, -1, -1, 0, 0, 1, 1, 1};
    const int DJ[8] = {-1,  0,  1, -1, 1, -1, 0, 1};

    h2 T0[4], T1[4], T2[4], T3[4], MK[4];

    #pragma unroll
    for (int p = 0; p < 4; ++p) {
        float f0[2], f1[2], f2[2], f3[2], mk[2];
        #pragma unroll
        for (int q = 0; q < 2; ++q) {
            const int k  = 2 * p + q;
            const int di = DI[k], dj = DJ[k];
            const int hh = h + di, ww = w + dj;
            const bool valid = ((unsigned)hh < (unsigned)HH) &
                               ((unsigned)ww < (unsigned)WW);
            const int ll = (l + di * 1024 + dj) & (LL - 1);  // clamped-safe addr
            const float ux = xb[ll];
            const float uM = Mb[ll];
            mk[q] = valid ? uM : 0.f;
            const int ts = (di + 1) * 258 + cl + dj;
            const h2 pa = uash2(tA[ts]);
            const h2 pe = uash2(tE[ts]);
            const float sAu = (float)pa.x, cAu = (float)pa.y;
            const float sEu = (float)pe.x, cEu = (float)pe.y;
            // rotation: angle difference identities
            const float cA = __fmaf_rn(cAu, cAc, sAu * sAc);
            const float sA = __fmaf_rn(sAu, cAc, -(cAu * sAc));
            const float cE = __fmaf_rn(cEu, cEc, sEu * sEc);
            const float sE = __fmaf_rn(sEu, cEc, -(cEu * sEc));
            const float xcA = ux * cA;
            f0[q] = ux;
            f1[q] = __fmaf_rn(xcA, cE, -Xc);
            f2[q] = xcA * sE;
            f3[q] = ux * sA;
        }
        T0[p] = pk(f0[0], f0[1]);
        T1[p] = pk(f1[0], f1[1]);
        T2[p] = pk(f2[0], f2[1]);
        T3[p] = pk(f3[0], f3[1]);
        MK[p] = pk(mk[0], mk[1]);
    }

    const float xmX = xc - Xc;
    const int obase = (b * NO) << 16;   // uniform part of output index

    #pragma unroll 4
    for (int o = 0; o < NO; ++o) {
        // Guaranteed scalar weight load: 8 dwords via 2x s_load_dwordx4.
        // ws + o*8 is wave-uniform -> SGPR address; outputs land in SGPRs,
        // v_pk_fma_f16 consumes them directly (1 SGPR operand per VALU op).
        u32x4 wa, wc;
        const unsigned* wp = ws + o * 8;
        asm("s_load_dwordx4 %0, %2, 0x0\n\t"
            "s_load_dwordx4 %1, %2, 0x10\n\t"
            "s_waitcnt lgkmcnt(0)"
            : "=&s"(wa), "=&s"(wc)
            : "s"(wp));
        const h2 w0 = uash2(wa.x), w1 = uash2(wa.y);
        const h2 w2 = uash2(wa.z), w3 = uash2(wa.w);
        const h2 wb = uash2(wc.x);
        const float w0f = uasf(wc.y), w1f = uasf(wc.z), bf = uasf(wc.w);

        h2 m2;
        #pragma unroll
        for (int p = 0; p < 4; ++p) {
            h2 s = fma2(w0, T0[p], wb);
            s = fma2(w1, T1[p], s);
            s = fma2(w2, T2[p], s);
            s = fma2(w3, T3[p], s);
            s = s * MK[p];
            m2 = (p == 0) ? s : max2(m2, s);
        }
        // center tap in f32 (t2=t3=0, mask folded: out = max(...)*Mc)
        const float sc = __fmaf_rn(w0f, xc, __fmaf_rn(w1f, xmX, bf));
        const float vc = sc * Mc;
        const float m  = fmaxf(fmaxf((float)m2.x, (float)m2.y), vc);
        out[obase + (o << 16) + l] = m * Mc;
    }
}

extern "C" void kernel_launch(void* const* d_in, const int* in_sizes, int n_in,
                              void* d_out, int out_size, void* d_ws, size_t ws_size,
                              hipStream_t stream) {
    const float* x  = (const float*)d_in[0];
    const float* X  = (const float*)d_in[1];
    const float* A  = (const float*)d_in[2];
    const float* E  = (const float*)d_in[3];
    const float* M  = (const float*)d_in[4];
    const float* cw = (const float*)d_in[5];
    const float* cb = (const float*)d_in[6];
    float* out = (float*)d_out;
    unsigned* ws = (unsigned*)d_ws;

    prep_kernel<<<1, 64, 0, stream>>>(cw, cb, ws);
    pnc_kernel<<<BB * 64 * 4, 256, 0, stream>>>(x, X, A, E, M, ws, out);
}

// Round 5
// 30.919 us; speedup vs baseline: 1.1242x; 1.1242x over previous
//
#include <hip/hip_runtime.h>
#include <hip/hip_bf16.h>

#define NO 32
#define HH 64
#define WW 1024
#define LL (HH * WW)
#define BB 8

typedef _Float16 h2 __attribute__((ext_vector_type(2)));

__device__ __forceinline__ h2 pk(float a, float b) {
    return __builtin_bit_cast(h2, __builtin_amdgcn_cvt_pkrtz(a, b));
}
__device__ __forceinline__ h2 fma2(h2 a, h2 b, h2 c) {
    return __builtin_elementwise_fma(a, b, c);
}
__device__ __forceinline__ h2 max2(h2 a, h2 b) {
    return __builtin_elementwise_max(a, b);
}
__device__ __forceinline__ h2 uash2(unsigned u) {
    return __builtin_bit_cast(h2, u);
}
__device__ __forceinline__ unsigned h2asu(h2 h) {
    return __builtin_bit_cast(unsigned, h);
}

__global__ __launch_bounds__(256, 4) void pnc_kernel(
    const float* __restrict__ x, const float* __restrict__ X,
    const float* __restrict__ A, const float* __restrict__ E,
    const float* __restrict__ M, const float* __restrict__ cw,
    const float* __restrict__ cb, float* __restrict__ out)
{
    // LDS: only sincos tiles (f16x2 [sin,cos]) over 3 rows x 258 cols halo
    __shared__ unsigned tA[3 * 258];
    __shared__ unsigned tE[3 * 258];

    const int tid = threadIdx.x;
    const int bi  = blockIdx.x;
    const int b   = bi >> 8;           // 256 blocks per image (64 h x 4 col-quarters)
    const int h   = (bi >> 2) & 63;
    const int w0q = (bi & 3) << 8;
    const int w   = w0q + tid;
    const int l   = (h << 10) + w;

    const float* xb = x + b * LL;
    const float* Xb = X + b * LL;
    const float* Ab = A + b * LL;
    const float* Eb = E + b * LL;
    const float* Mb = M + b * LL;

    // ---- sincos tile fill: 3 rows x 258 cols of raw A, E angles ----
    for (int s = tid; s < 3 * 258; s += 256) {
        const int r = (s >= 516) ? 2 : ((s >= 258) ? 1 : 0);
        const int c = s - r * 258;
        int gh = h - 1 + r; gh = min(max(gh, 0), HH - 1);
        int gw = w0q - 1 + c; gw = min(max(gw, 0), WW - 1);
        const int gl = (gh << 10) + gw;
        const float a = Ab[gl], e = Eb[gl];
        float sa, ca, se, ce;
        __sincosf(a, &sa, &ca);
        __sincosf(e, &se, &ce);
        tA[s] = h2asu(pk(sa, ca));
        tE[s] = h2asu(pk(se, ce));
    }
    __syncthreads();

    // ---- center values ----
    const float xc = xb[l];
    const float Xc = Xb[l];
    const float Mc = Mb[l];
    const int   cl = tid + 1;
    const h2 cpA = uash2(tA[258 + cl]);
    const h2 cpE = uash2(tE[258 + cl]);
    const float sAc = (float)cpA.x, cAc = (float)cpA.y;
    const float sEc = (float)cpE.x, cEc = (float)cpE.y;

    // ---- 8 off-center taps -> 4 packed f16x2 pairs ----
    // tap order (di,dj): (-1,-1)(-1,0)(-1,1)(0,-1)(0,1)(1,-1)(1,0)(1,1)
    const int DI[8] = {-1, -1, -1, 0, 0, 1, 1, 1};
    const int DJ[8] = {-1,  0,  1, -1, 1, -1, 0, 1};

    h2 T0[4], T1[4], T2[4], T3[4], MK[4];

    #pragma unroll
    for (int p = 0; p < 4; ++p) {
        float f0[2], f1[2], f2[2], f3[2], mk[2];
        #pragma unroll
        for (int q = 0; q < 2; ++q) {
            const int k  = 2 * p + q;
            const int di = DI[k], dj = DJ[k];
            const int hh = h + di, ww = w + dj;
            const bool valid = ((unsigned)hh < (unsigned)HH) &
                               ((unsigned)ww < (unsigned)WW);
            const int ll = (l + di * 1024 + dj) & (LL - 1);  // clamped-safe addr
            const float ux = xb[ll];
            const float uM = Mb[ll];
            mk[q] = valid ? uM : 0.f;
            const int ts = (di + 1) * 258 + cl + dj;
            const h2 pa = uash2(tA[ts]);
            const h2 pe = uash2(tE[ts]);
            const float sAu = (float)pa.x, cAu = (float)pa.y;
            const float sEu = (float)pe.x, cEu = (float)pe.y;
            // rotation: angle difference identities
            const float cA = __fmaf_rn(cAu, cAc, sAu * sAc);
            const float sA = __fmaf_rn(sAu, cAc, -(cAu * sAc));
            const float cE = __fmaf_rn(cEu, cEc, sEu * sEc);
            const float sE = __fmaf_rn(sEu, cEc, -(cEu * sEc));
            const float xcA = ux * cA;
            f0[q] = ux;
            f1[q] = __fmaf_rn(xcA, cE, -Xc);
            f2[q] = xcA * sE;
            f3[q] = ux * sA;
        }
        T0[p] = pk(f0[0], f0[1]);
        T1[p] = pk(f1[0], f1[1]);
        T2[p] = pk(f2[0], f2[1]);
        T3[p] = pk(f3[0], f3[1]);
        MK[p] = pk(mk[0], mk[1]);
    }

    const float xmX = xc - Xc;
    float* ob = out + b * (NO * LL) + l;
    const float4* cw4 = (const float4*)cw;

    #pragma unroll 4
    for (int o = 0; o < NO; ++o) {
        // Wave-uniform weight loads -> compiler scalarizes to s_load on the
        // SMEM pipe (separate from VALU and LDS). Duplicated f16 pairs built
        // in-register with cvt_pkrtz (5 VALU/o).
        const float4 wv = cw4[o];
        const float bo = cb[o];
        const h2 w0 = pk(wv.x, wv.x);
        const h2 w1 = pk(wv.y, wv.y);
        const h2 w2 = pk(wv.z, wv.z);
        const h2 w3 = pk(wv.w, wv.w);
        const h2 wb = pk(bo, bo);

        h2 m2;
        #pragma unroll
        for (int p = 0; p < 4; ++p) {
            h2 s = fma2(w0, T0[p], wb);
            s = fma2(w1, T1[p], s);
            s = fma2(w2, T2[p], s);
            s = fma2(w3, T3[p], s);
            s = s * MK[p];
            m2 = (p == 0) ? s : max2(m2, s);
        }
        // center tap in f32 (t2=t3=0; out scaled by Mc at the end)
        const float sc = __fmaf_rn(wv.x, xc, __fmaf_rn(wv.y, xmX, bo));
        const float vc = sc * Mc;
        const float m  = fmaxf(fmaxf((float)m2.x, (float)m2.y), vc);
        ob[o * LL] = m * Mc;
    }
}

extern "C" void kernel_launch(void* const* d_in, const int* in_sizes, int n_in,
                              void* d_out, int out_size, void* d_ws, size_t ws_size,
                              hipStream_t stream) {
    const float* x  = (const float*)d_in[0];
    const float* X  = (const float*)d_in[1];
    const float* A  = (const float*)d_in[2];
    const float* E  = (const float*)d_in[3];
    const float* M  = (const float*)d_in[4];
    const float* cw = (const float*)d_in[5];
    const float* cb = (const float*)d_in[6];
    float* out = (float*)d_out;

    pnc_kernel<<<BB * 64 * 4, 256, 0, stream>>>(x, X, A, E, M, cw, cb, out);
}

// Round 6
// 26.725 us; speedup vs baseline: 1.3007x; 1.1569x over previous
//
#include <hip/hip_runtime.h>
#include <hip/hip_bf16.h>

#define NO 32
#define HH 64
#define WW 1024
#define LL (HH * WW)
#define BB 8

typedef _Float16 h2 __attribute__((ext_vector_type(2)));

__device__ __forceinline__ h2 pk(float a, float b) {
    return __builtin_bit_cast(h2, __builtin_amdgcn_cvt_pkrtz(a, b));
}
__device__ __forceinline__ h2 fma2(h2 a, h2 b, h2 c) {
    return __builtin_elementwise_fma(a, b, c);
}
__device__ __forceinline__ h2 max2(h2 a, h2 b) {
    return __builtin_elementwise_max(a, b);
}
__device__ __forceinline__ h2 uash2(unsigned u) {
    return __builtin_bit_cast(h2, u);
}
__device__ __forceinline__ unsigned h2asu(h2 h) {
    return __builtin_bit_cast(unsigned, h);
}

__global__ __launch_bounds__(256, 6) void pnc_kernel(
    const float* __restrict__ x, const float* __restrict__ X,
    const float* __restrict__ A, const float* __restrict__ E,
    const float* __restrict__ M, const float* __restrict__ cw,
    const float* __restrict__ cb, float* __restrict__ out)
{
    __shared__ unsigned tA[3 * 258];
    __shared__ unsigned tE[3 * 258];

    const int tid = threadIdx.x;
    const int bi  = blockIdx.x;
    const int b   = bi >> 8;           // 256 blocks per image (64 h x 4 col-quarters)
    const int h   = (bi >> 2) & 63;
    const int w0q = (bi & 3) << 8;
    const int w   = w0q + tid;
    const int l   = (h << 10) + w;

    const float* xb = x + b * LL;
    const float* Xb = X + b * LL;
    const float* Ab = A + b * LL;
    const float* Eb = E + b * LL;
    const float* Mb = M + b * LL;

    // ================= issue ALL global loads up front =================
    // (a) fill-phase A/E loads, fully unrolled (3 full strides + 6-elem tail)
    float av[4], ev[4];
    int   sv[4];
    #pragma unroll
    for (int i = 0; i < 4; ++i) {
        const int s = tid + (i << 8);
        sv[i] = s;
        const int r = (s >= 516) ? 2 : ((s >= 258) ? 1 : 0);
        const int c = s - r * 258;
        int gh = h - 1 + r; gh = min(max(gh, 0), HH - 1);
        int gw = w0q - 1 + c; gw = min(max(gw, 0), WW - 1);
        const int gl = (gh << 10) + gw;
        if (i < 3) { av[i] = Ab[gl]; ev[i] = Eb[gl]; }
        else if (s < 774) { av[3] = Ab[gl]; ev[3] = Eb[gl]; }
        else { av[3] = 0.f; ev[3] = 0.f; }
    }
    // (b) 9-tap x and M loads + center X
    float xr[9], mr[9];
    #pragma unroll
    for (int k = 0; k < 9; ++k) {
        const int di = k / 3 - 1, dj = k % 3 - 1;
        const int ll = (l + di * 1024 + dj) & (LL - 1);  // wrap-safe addr
        xr[k] = xb[ll];
        mr[k] = Mb[ll];
    }
    const float Xc = Xb[l];

    // ================= sincos + LDS fill =================
    #pragma unroll
    for (int i = 0; i < 4; ++i) {
        if (i == 3 && sv[3] >= 774) continue;
        float sa, ca, se, ce;
        __sincosf(av[i], &sa, &ca);
        __sincosf(ev[i], &se, &ce);
        tA[sv[i]] = h2asu(pk(sa, ca));
        tE[sv[i]] = h2asu(pk(se, ce));
    }
    __syncthreads();

    // ================= center values =================
    const float xc = xr[4];
    const float Mc = mr[4];
    const int   cl = tid + 1;
    const h2 cpA = uash2(tA[258 + cl]);
    const h2 cpE = uash2(tE[258 + cl]);
    const float sAc = (float)cpA.x, cAc = (float)cpA.y;
    const float sEc = (float)cpE.x, cEc = (float)cpE.y;

    // ================= 8 off-center taps -> 4 packed pairs =================
    // pair order over k (skipping center k=4): (0,1)(2,3)(5,6)(7,8)
    const int KS[8] = {0, 1, 2, 3, 5, 6, 7, 8};

    h2 T0[4], T1[4], T2[4], T3[4], MK[4];

    #pragma unroll
    for (int p = 0; p < 4; ++p) {
        float f0[2], f1[2], f2[2], f3[2], mk[2];
        #pragma unroll
        for (int q = 0; q < 2; ++q) {
            const int k  = KS[2 * p + q];
            const int di = k / 3 - 1, dj = k % 3 - 1;
            const int hh = h + di, ww = w + dj;
            const bool valid = ((unsigned)hh < (unsigned)HH) &
                               ((unsigned)ww < (unsigned)WW);
            const float ux = xr[k];
            mk[q] = valid ? (Mc * mr[k]) : 0.f;   // Mc folded in here
            const int ts = (di + 1) * 258 + cl + dj;
            const h2 pa = uash2(tA[ts]);
            const h2 pe = uash2(tE[ts]);
            const float sAu = (float)pa.x, cAu = (float)pa.y;
            const float sEu = (float)pe.x, cEu = (float)pe.y;
            // angle-difference identities
            const float cA = __fmaf_rn(cAu, cAc, sAu * sAc);
            const float sA = __fmaf_rn(sAu, cAc, -(cAu * sAc));
            const float cE = __fmaf_rn(cEu, cEc, sEu * sEc);
            const float sE = __fmaf_rn(sEu, cEc, -(cEu * sEc));
            const float xcA = ux * cA;
            f0[q] = ux;
            f1[q] = __fmaf_rn(xcA, cE, -Xc);
            f2[q] = xcA * sE;
            f3[q] = ux * sA;
        }
        T0[p] = pk(f0[0], f0[1]);
        T1[p] = pk(f1[0], f1[1]);
        T2[p] = pk(f2[0], f2[1]);
        T3[p] = pk(f3[0], f3[1]);
        MK[p] = pk(mk[0], mk[1]);
    }

    const float xmX = xc - Xc;
    float* ob = out + b * (NO * LL) + l;
    const float4* cw4 = (const float4*)cw;

    #pragma unroll 4
    for (int o = 0; o < NO; ++o) {
        // wave-uniform weight loads -> scalarized to s_load on the SMEM pipe
        const float4 wv = cw4[o];
        const float bo = cb[o];
        const h2 w0 = pk(wv.x, wv.x);
        const h2 w1 = pk(wv.y, wv.y);
        const h2 w2 = pk(wv.z, wv.z);
        const h2 w3 = pk(wv.w, wv.w);
        const h2 wb = pk(bo, bo);

        h2 m2;
        #pragma unroll
        for (int p = 0; p < 4; ++p) {
            h2 s = fma2(w0, T0[p], wb);
            s = fma2(w1, T1[p], s);
            s = fma2(w2, T2[p], s);
            s = fma2(w3, T3[p], s);
            s = s * MK[p];
            m2 = (p == 0) ? s : max2(m2, s);
        }
        // center tap in f32 (t2=t3=0; mask = Mc, M values are exact 0/1)
        const float sc = __fmaf_rn(wv.x, xc, __fmaf_rn(wv.y, xmX, bo));
        const float vc = sc * Mc;
        const float m  = fmaxf(fmaxf((float)m2.x, (float)m2.y), vc);
        __builtin_nontemporal_store(m, &ob[o * LL]);
    }
}

extern "C" void kernel_launch(void* const* d_in, const int* in_sizes, int n_in,
                              void* d_out, int out_size, void* d_ws, size_t ws_size,
                              hipStream_t stream) {
    const float* x  = (const float*)d_in[0];
    const float* X  = (const float*)d_in[1];
    const float* A  = (const float*)d_in[2];
    const float* E  = (const float*)d_in[3];
    const float* M  = (const float*)d_in[4];
    const float* cw = (const float*)d_in[5];
    const float* cb = (const float*)d_in[6];
    float* out = (float*)d_out;

    pnc_kernel<<<BB * 64 * 4, 256, 0, stream>>>(x, X, A, E, M, cw, cb, out);
}

// Round 7
// 26.417 us; speedup vs baseline: 1.3159x; 1.0117x over previous
//
#include <hip/hip_runtime.h>
#include <hip/hip_bf16.h>

#define NO 32
#define HH 64
#define WW 1024
#define LL (HH * WW)
#define BB 8
#define TW 514
#define TSZ (3 * TW)   // 1542

typedef _Float16 h2 __attribute__((ext_vector_type(2)));
typedef float f32x2 __attribute__((ext_vector_type(2)));

__device__ __forceinline__ h2 pk(float a, float b) {
    return __builtin_bit_cast(h2, __builtin_amdgcn_cvt_pkrtz(a, b));
}
__device__ __forceinline__ h2 fma2(h2 a, h2 b, h2 c) {
    return __builtin_elementwise_fma(a, b, c);
}
__device__ __forceinline__ h2 max2(h2 a, h2 b) {
    return __builtin_elementwise_max(a, b);
}
__device__ __forceinline__ h2 uash2(unsigned u) {
    return __builtin_bit_cast(h2, u);
}
__device__ __forceinline__ unsigned h2asu(h2 h) {
    return __builtin_bit_cast(unsigned, h);
}

__global__ __launch_bounds__(256, 4) void pnc_kernel(
    const float* __restrict__ x, const float* __restrict__ X,
    const float* __restrict__ A, const float* __restrict__ E,
    const float* __restrict__ M, const float* __restrict__ cw,
    const float* __restrict__ cb, float* __restrict__ out)
{
    __shared__ unsigned tA[TSZ];
    __shared__ unsigned tE[TSZ];

    const int tid  = threadIdx.x;
    const int bi   = blockIdx.x;
    const int b    = bi >> 7;          // 128 blocks per image (64 h x 2 halves)
    const int h    = (bi >> 1) & 63;
    const int half = bi & 1;
    const int wbase = half << 9;       // 0 or 512
    const int w0 = wbase + (tid << 1); // even; this thread owns pixels w0, w0+1
    const int l0 = (h << 10) + w0;

    const float* xb = x + b * LL;
    const float* Xb = X + b * LL;
    const float* Ab = A + b * LL;
    const float* Eb = E + b * LL;
    const float* Mb = M + b * LL;

    // ============ issue ALL global loads up front ============
    // (a) tile-fill A/E loads: 1542 entries, 6 full rounds + 6-elem tail
    float av[7], ev[7];
    int   sv[7];
    #pragma unroll
    for (int i = 0; i < 7; ++i) {
        const int s = tid + (i << 8);
        sv[i] = s;
        const int r = (s >= 2 * TW) ? 2 : ((s >= TW) ? 1 : 0);
        const int c = s - r * TW;
        int gh = h - 1 + r;     gh = min(max(gh, 0), HH - 1);
        int gw = wbase - 1 + c; gw = min(max(gw, 0), WW - 1);
        const int gl = (gh << 10) + gw;
        if (i < 6 || s < TSZ) { av[i] = Ab[gl]; ev[i] = Eb[gl]; }
        else { av[i] = 0.f; ev[i] = 0.f; }
    }

    // (b) shared tap loads: 3 rows x 4 cols (covers both pixels' 9-taps)
    float xr[12], mv[12];
    {
        const bool vr0 = (h > 0), vr2 = (h < HH - 1);
        const bool vc0 = (w0 > 0), vc3 = (w0 < WW - 2);
        #pragma unroll
        for (int r = 0; r < 3; ++r) {
            #pragma unroll
            for (int c = 0; c < 4; ++c) {
                const int idx = (r << 2) + c;
                const int ll  = (l0 + (r - 1) * 1024 + (c - 1)) & (LL - 1); // wrap-safe
                xr[idx] = xb[ll];
                const bool vr = (r == 1) | ((r == 0) ? vr0 : vr2);
                const bool vc = (c == 0) ? vc0 : ((c == 3) ? vc3 : true);
                const float m = Mb[ll];
                mv[idx] = (vr & vc) ? m : 0.f;
            }
        }
    }
    const f32x2 Xc2 = *reinterpret_cast<const f32x2*>(Xb + l0);

    // ============ sincos + LDS tile fill ============
    #pragma unroll
    for (int i = 0; i < 7; ++i) {
        if (i == 6 && sv[6] >= TSZ) continue;
        float sa, ca, se, ce;
        __sincosf(av[i], &sa, &ca);
        __sincosf(ev[i], &se, &ce);
        tA[sv[i]] = h2asu(pk(sa, ca));
        tE[sv[i]] = h2asu(pk(se, ce));
    }
    __syncthreads();

    // ============ per-pixel packed features ============
    h2 T0[2][4], T1[2][4], T2[2][4], T3[2][4], MK[2][4];
    float xcv[2], Mcv[2];
    const float Xcv[2] = {Xc2.x, Xc2.y};

    // off-center taps (r, cl) excluding center (1,1); cl in {0,1,2} == dj+1
    const int TR[8] = {0, 0, 0, 1, 1, 2, 2, 2};
    const int TC[8] = {0, 1, 2, 0, 2, 0, 1, 2};

    #pragma unroll
    for (int px = 0; px < 2; ++px) {
        const int tc = (tid << 1) + px;           // tile col of the dj=-1 tap
        const float xc = xr[5 + px];
        const float Mc = mv[5 + px];
        xcv[px] = xc; Mcv[px] = Mc;
        const float Xc = Xcv[px];
        const h2 cpA = uash2(tA[TW + tc + 1]);
        const h2 cpE = uash2(tE[TW + tc + 1]);
        const float sAc = (float)cpA.x, cAc = (float)cpA.y;
        const float sEc = (float)cpE.x, cEc = (float)cpE.y;

        #pragma unroll
        for (int p = 0; p < 4; ++p) {
            float f0[2], f1[2], f2[2], f3[2], mk[2];
            #pragma unroll
            for (int q = 0; q < 2; ++q) {
                const int k  = 2 * p + q;
                const int r  = TR[k], cl = TC[k];
                const int idx = (r << 2) + px + cl;
                const float ux = xr[idx];
                mk[q] = Mc * mv[idx];
                const int ts = r * TW + tc + cl;
                const h2 pa = uash2(tA[ts]);
                const h2 pe = uash2(tE[ts]);
                const float sAu = (float)pa.x, cAu = (float)pa.y;
                const float sEu = (float)pe.x, cEu = (float)pe.y;
                const float cA = __fmaf_rn(cAu, cAc, sAu * sAc);
                const float sA = __fmaf_rn(sAu, cAc, -(cAu * sAc));
                const float cE = __fmaf_rn(cEu, cEc, sEu * sEc);
                const float sE = __fmaf_rn(sEu, cEc, -(cEu * sEc));
                const float xcA = ux * cA;
                f0[q] = ux;
                f1[q] = __fmaf_rn(xcA, cE, -Xc);
                f2[q] = xcA * sE;
                f3[q] = ux * sA;
            }
            T0[px][p] = pk(f0[0], f0[1]);
            T1[px][p] = pk(f1[0], f1[1]);
            T2[px][p] = pk(f2[0], f2[1]);
            T3[px][p] = pk(f3[0], f3[1]);
            MK[px][p] = pk(mk[0], mk[1]);
        }
    }

    const float xmX[2] = {xcv[0] - Xcv[0], xcv[1] - Xcv[1]};
    float* ob = out + b * (NO * LL) + l0;
    const float4* cw4 = (const float4*)cw;

    #pragma unroll 4
    for (int o = 0; o < NO; ++o) {
        // wave-uniform weight loads -> s_load on SMEM pipe
        const float4 wv = cw4[o];
        const float bo = cb[o];
        const h2 w0h = pk(wv.x, wv.x);
        const h2 w1h = pk(wv.y, wv.y);
        const h2 w2h = pk(wv.z, wv.z);
        const h2 w3h = pk(wv.w, wv.w);
        const h2 wbh = pk(bo, bo);

        f32x2 st;
        #pragma unroll
        for (int px = 0; px < 2; ++px) {
            h2 m2;
            #pragma unroll
            for (int p = 0; p < 4; ++p) {
                h2 s = fma2(w0h, T0[px][p], wbh);
                s = fma2(w1h, T1[px][p], s);
                s = fma2(w2h, T2[px][p], s);
                s = fma2(w3h, T3[px][p], s);
                s = s * MK[px][p];
                m2 = (p == 0) ? s : max2(m2, s);
            }
            // center tap in f32 (t2=t3=0, mask = Mc)
            const float sc = __fmaf_rn(wv.x, xcv[px], __fmaf_rn(wv.y, xmX[px], bo));
            const float vc = sc * Mcv[px];
            st[px] = fmaxf(fmaxf((float)m2.x, (float)m2.y), vc);
        }
        // 512B-contiguous per-wave store, 2KB-contiguous per block per o-plane
        __builtin_nontemporal_store(st, reinterpret_cast<f32x2*>(ob + o * LL));
    }
}

extern "C" void kernel_launch(void* const* d_in, const int* in_sizes, int n_in,
                              void* d_out, int out_size, void* d_ws, size_t ws_size,
                              hipStream_t stream) {
    const float* x  = (const float*)d_in[0];
    const float* X  = (const float*)d_in[1];
    const float* A  = (const float*)d_in[2];
    const float* E  = (const float*)d_in[3];
    const float* M  = (const float*)d_in[4];
    const float* cw = (const float*)d_in[5];
    const float* cb = (const float*)d_in[6];
    float* out = (float*)d_out;

    pnc_kernel<<<BB * 64 * 2, 256, 0, stream>>>(x, X, A, E, M, cw, cb, out);
}

// Round 8
// 18.246 us; speedup vs baseline: 1.9051x; 1.4478x over previous
//
#include <hip/hip_runtime.h>
#include <hip/hip_bf16.h>

#define NO 32
#define HH 64
#define WW 1024
#define LL (HH * WW)
#define BB 8

typedef _Float16 h2 __attribute__((ext_vector_type(2)));
typedef _Float16 v8h __attribute__((ext_vector_type(8)));
typedef float f32x16 __attribute__((ext_vector_type(16)));
typedef unsigned u32x4v __attribute__((ext_vector_type(4)));

static __device__ __forceinline__ unsigned pku(float a, float b) {
    return __builtin_bit_cast(unsigned, __builtin_amdgcn_cvt_pkrtz(a, b));
}
static __device__ __forceinline__ float lo16f(unsigned u) {
    return (float)__builtin_bit_cast(h2, u).x;
}
static __device__ __forceinline__ float hi16f(unsigned u) {
    return (float)__builtin_bit_cast(h2, u).y;
}

__global__ __launch_bounds__(256, 4) void pnc_kernel(
    const float* __restrict__ x, const float* __restrict__ X,
    const float* __restrict__ A, const float* __restrict__ E,
    const float* __restrict__ M, const float* __restrict__ cw,
    const float* __restrict__ cb, float* __restrict__ out)
{
    __shared__ unsigned tA[774];   // 3 rows x 258 cols, f16x2 [sin,cos]
    __shared__ unsigned tE[774];

    const int tid = threadIdx.x;
    const int bi  = blockIdx.x;
    const int b   = bi >> 8;          // 256 blocks/image: 64 h x 4 quarters
    const int h   = (bi >> 2) & 63;
    const int wq  = (bi & 3) << 8;
    const int w   = wq + tid;
    const int l   = (h << 10) + w;

    const float* xb = x + b * LL;
    const float* Xb = X + b * LL;
    const float* Ab = A + b * LL;
    const float* Eb = E + b * LL;
    const float* Mb = M + b * LL;

    // ================= issue ALL global loads up front =================
    float av[4], ev[4];
    int   sv[4];
    #pragma unroll
    for (int i = 0; i < 4; ++i) {
        const int s = tid + (i << 8);
        sv[i] = s;
        const int r = (s >= 516) ? 2 : ((s >= 258) ? 1 : 0);
        const int c = s - r * 258;
        int gh = h - 1 + r;  gh = min(max(gh, 0), HH - 1);
        int gw = wq - 1 + c; gw = min(max(gw, 0), WW - 1);
        const int gl = (gh << 10) + gw;
        if (i < 3 || s < 774) { av[i] = Ab[gl]; ev[i] = Eb[gl]; }
        else { av[i] = 0.f; ev[i] = 0.f; }
    }
    // per-lane weight row (o = lane&31)
    const int o_ln = tid & 31;
    const float4 wv = ((const float4*)cw)[o_ln];
    const float  bo = cb[o_ln];
    // 9-tap x/M + center X
    float xr[9], mr[9];
    #pragma unroll
    for (int k = 0; k < 9; ++k) {
        const int di = k / 3 - 1, dj = k % 3 - 1;
        const int ll = (l + di * 1024 + dj) & (LL - 1);  // wrap-safe
        xr[k] = xb[ll];
        mr[k] = Mb[ll];
    }
    const float Xc = Xb[l];

    // ================= sincos + LDS tile fill =================
    #pragma unroll
    for (int i = 0; i < 4; ++i) {
        if (i == 3 && sv[3] >= 774) continue;
        float sa, ca, se, ce;
        __sincosf(av[i], &sa, &ca);
        __sincosf(ev[i], &se, &ce);
        tA[sv[i]] = pku(sa, ca);
        tE[sv[i]] = pku(se, ce);
    }
    __syncthreads();

    // ================= center sincos from tile =================
    const float xc = xr[4];
    const float Mc = mr[4];
    const int   cl = tid + 1;
    const unsigned cA_ = tA[258 + cl], cE_ = tE[258 + cl];
    const float sAc = lo16f(cA_), cAc = hi16f(cA_);
    const float sEc = lo16f(cE_), cEc = hi16f(cE_);

    // ================= A fragments (weights) =================
    // row o = lane&31, k-slots: [w0,w1,w2,w3,b,0,0,0]
    // A1: k0..7 live in lanes<32 (covers B's lanes<32 = px 0..31)
    // A2: k8..15 live in lanes>=32 (covers B's lanes>=32 = px 32..63)
    const unsigned a0 = pku(wv.x, wv.y);
    const unsigned a1 = pku(wv.z, wv.w);
    const unsigned a2 = pku(bo, 0.f);
    const bool lol = ((tid & 63) < 32);
    const v8h A1 = __builtin_bit_cast(v8h,
        (u32x4v){lol ? a0 : 0u, lol ? a1 : 0u, lol ? a2 : 0u, 0u});
    const v8h A2 = __builtin_bit_cast(v8h,
        (u32x4v){lol ? 0u : a0, lol ? 0u : a1, lol ? 0u : a2, 0u});

    f32x16 zz;
    #pragma unroll
    for (int i = 0; i < 16; ++i) zz[i] = 0.f;

    // ================= fused tap loop: features -> MFMA -> max =================
    f32x16 R1, R2;
    #pragma unroll
    for (int k = 0; k < 9; ++k) {
        const int r  = k / 3;           // 0..2
        const int cc = k % 3;           // 0..2
        const int hh = h + r - 1, ww = w + cc - 1;
        const bool valid = ((unsigned)hh < (unsigned)HH) &
                           ((unsigned)ww < (unsigned)WW);
        const float ux = xr[k];
        const float mm = valid ? (Mc * mr[k]) : 0.f;   // in {0,1}
        const int ts = r * 258 + tid + cc;
        const unsigned pa = tA[ts], pe = tE[ts];
        const float sAu = lo16f(pa), cAu = hi16f(pa);
        const float sEu = lo16f(pe), cEu = hi16f(pe);
        // angle-difference identities
        const float cA2 = __fmaf_rn(cAu, cAc, sAu * sAc);
        const float sA2 = __fmaf_rn(sAu, cAc, -(cAu * sAc));
        const float cE2 = __fmaf_rn(cEu, cEc, sEu * sEc);
        const float sE2 = __fmaf_rn(sEu, cEc, -(cEu * sEc));
        const float xcA = ux * cA2;
        const float f0 = ux;
        const float f1 = __fmaf_rn(xcA, cE2, -Xc);
        const float f2 = xcA * sE2;
        const float f3 = ux * sA2;
        // masked feature vector [m*f0, m*f1, m*f2, m*f3, m, 0, ...]
        const v8h Bk = __builtin_bit_cast(v8h,
            (u32x4v){pku(mm * f0, mm * f1), pku(mm * f2, mm * f3),
                     pku(mm, 0.f), 0u});
        const f32x16 D1 = __builtin_amdgcn_mfma_f32_32x32x16_f16(A1, Bk, zz, 0, 0, 0);
        const f32x16 D2 = __builtin_amdgcn_mfma_f32_32x32x16_f16(A2, Bk, zz, 0, 0, 0);
        if (k == 0) { R1 = D1; R2 = D2; }
        else {
            R1 = __builtin_elementwise_max(R1, D1);
            R2 = __builtin_elementwise_max(R2, D2);
        }
    }

    // ================= store: D col=lane&31, row=(reg&3)+8*(reg>>2)+4*(lane>>5)
    const int lane = tid & 63;
    const int wid  = tid >> 6;
    const int c31  = lane & 31;
    const int hi   = lane >> 5;
    float* ob0 = out + (b * NO + hi * 4) * LL + (h << 10) + wq + (wid << 6) + c31;
    #pragma unroll
    for (int i = 0; i < 16; ++i) {
        const int oo = (i & 3) + 8 * (i >> 2);
        __builtin_nontemporal_store(R1[i], ob0 + oo * LL);        // px 0..31
        __builtin_nontemporal_store(R2[i], ob0 + oo * LL + 32);   // px 32..63
    }
}

extern "C" void kernel_launch(void* const* d_in, const int* in_sizes, int n_in,
                              void* d_out, int out_size, void* d_ws, size_t ws_size,
                              hipStream_t stream) {
    const float* x  = (const float*)d_in[0];
    const float* X  = (const float*)d_in[1];
    const float* A  = (const float*)d_in[2];
    const float* E  = (const float*)d_in[3];
    const float* M  = (const float*)d_in[4];
    const float* cw = (const float*)d_in[5];
    const float* cb = (const float*)d_in[6];
    float* out = (float*)d_out;

    pnc_kernel<<<BB * 64 * 4, 256, 0, stream>>>(x, X, A, E, M, cw, cb, out);
}